// Round 5
// baseline (124.485 us; speedup 1.0000x reference)
//
#include <hip/hip_runtime.h>
#include <hip/hip_bf16.h>
#include <math.h>

// Problem constants
#define MM 12544   // 64 * 196 patches
#define KK 768     // 16*16*3
#define NN 768     // embedding dim
#define BM 64
#define BN 256
#define BK 64
#define KT 12              // KK/BK
#define MT 196             // MM/BM
#define NT 3               // NN/BN
#define TILE_B_BYTES (BN*BK*2)   // 32768

#define WTPACK_BLOCKS ((NN * 96) / 256)   // 288

typedef __bf16 v8bf __attribute__((ext_vector_type(8)));
typedef float  v4f  __attribute__((ext_vector_type(4)));

// ---------------------------------------------------------------------------
// W-pack only (A is now im2col'd inline in the GEMM): W [k][n] fp32 ->
// [nt 0..2][kt 0..11][n 0..255][g^(n&7)][8] bf16. ~3.6 MB traffic, ~1.5 us.
// ---------------------------------------------------------------------------
__global__ __launch_bounds__(256) void wt_pack(const float* __restrict__ w,
                                               __hip_bfloat16* __restrict__ wpack) {
    int tid = blockIdx.x * 256 + threadIdx.x;   // 0 .. 768*96-1
    int n   = tid % 768;
    int gg  = tid / 768;
    int k0  = gg * 8;
    float f[8];
#pragma unroll
    for (int j = 0; j < 8; j++) f[j] = w[(size_t)(k0 + j) * NN + n];
    int nt = n >> 8;        // 256-col tiles
    int nr = n & 255;
    int kt = gg >> 3;
    int g  = gg & 7;
    int gs = g ^ (nr & 7);
    union { __hip_bfloat16 h[8]; uint4 u; } o;
#pragma unroll
    for (int j = 0; j < 8; j++) o.h[j] = __float2bfloat16(f[j]);
    *(uint4*)(wpack + ((size_t)(nt * KT + kt) * BN + nr) * BK + gs * 8) = o.u;
}

// Fast GELU: x*E/(E+1), E=e^{2t}, t=0.79788456(x+0.044715x^3).
__device__ __forceinline__ float gelu_fast(float x) {
    float t2 = 1.5957691216057308f * x * (1.0f + 0.044715f * x * x);  // 2t
    float e  = __expf(t2);
    float r  = __builtin_amdgcn_rcpf(e + 1.0f);
    return x - x * r;
}

// ---------------------------------------------------------------------------
// Fused im2col + bf16 MFMA GEMM + bias + fast GELU.
// Block tile 64x256, 256 thr / 4 waves (wave = 64 rows x 64 cols).
// A-staging: inline im2col — per thread 4x float4 image loads + cvt +
// 2x ds_write_b128 into the xor-swizzled LDS layout (same layout the
// fragment ds_read_b128s expect). B-staging: global_load_lds from wpack,
// issued FIRST so its vmcnt drain overlaps the A-side VALU work.
// Thread t: r = t>>2 (A row / patch), q = t&3 (16-wide k-subrange).
// ---------------------------------------------------------------------------
__global__ __launch_bounds__(256, 3) void gemm_gelu(const float* __restrict__ img,
                                                    const __hip_bfloat16* __restrict__ wpack,
                                                    const float* __restrict__ bias,
                                                    float* __restrict__ out) {
    __shared__ __align__(16) __hip_bfloat16 As[BM * BK];   //  8 KB
    __shared__ __align__(16) __hip_bfloat16 Bs[BN * BK];   // 32 KB

    const int blk = blockIdx.x;
    const int nt  = blk % 3;
    const int mt  = blk / 3;

    const int tid  = threadIdx.x;
    const int lane = tid & 63;
    const int wave = tid >> 6;
    const int wn   = wave * 64;          // wave's N-offset within tile
    const int col  = lane & 15;
    const int quad = lane >> 4;
    const int cl7  = col & 7;

    // --- per-thread im2col geometry (computed once) ---
    const int r = tid >> 2;              // A row within tile = patch offset
    const int q = tid & 3;               // k-subrange [q*16, q*16+16)
    unsigned m  = (unsigned)(mt * BM + r);
    unsigned b  = m / 196u;
    unsigned pm = m - b * 196u;
    unsigned pr = pm / 14u;
    unsigned pc = pm - pr * 14u;
    const float* pbase = img + (size_t)(((b * 224u + pr * 16u) * 224u + pc * 16u) * 3u);
    const int gs0 = (2 * q) ^ (r & 7);       // swizzled slot for group 2q
    const int gs1 = gs0 ^ 1;                 // group 2q+1
    uint4* As16 = (uint4*)As;

    v4f acc[4][4];
    const v4f vzero = {0.f, 0.f, 0.f, 0.f};
#pragma unroll
    for (int a = 0; a < 4; a++)
#pragma unroll
        for (int c = 0; c < 4; c++) acc[a][c] = vzero;

    const char* bT = (const char*)wpack + (size_t)nt * KT * TILE_B_BYTES;

    for (int kt = 0; kt < KT; kt++) {
        // ---- B: 32 KB via global_load_lds (8 x 16B per thread), issue first ----
#pragma unroll
        for (int p = 0; p < 8; p++) {
            int off = p * 4096 + tid * 16;
            __builtin_amdgcn_global_load_lds(
                (const __attribute__((address_space(1))) void*)(bT + off),
                (__attribute__((address_space(3))) void*)((char*)Bs + off), 16, 0, 0);
        }
        bT += TILE_B_BYTES;

        // ---- A: inline im2col, 16 fp32 -> 16 bf16 per thread ----
        float4 f4[4];
#pragma unroll
        for (int j = 0; j < 4; j++) {
            unsigned k   = (unsigned)(kt * 64 + q * 16 + j * 4);
            unsigned i   = k / 48u;               // row within patch
            unsigned rem = k - i * 48u;           // float4-aligned, <=44
            f4[j] = *(const float4*)(pbase + i * 672u + rem);
        }
        union { __hip_bfloat16 h[8]; uint4 u; } lo, hi;
        lo.h[0] = __float2bfloat16(f4[0].x); lo.h[1] = __float2bfloat16(f4[0].y);
        lo.h[2] = __float2bfloat16(f4[0].z); lo.h[3] = __float2bfloat16(f4[0].w);
        lo.h[4] = __float2bfloat16(f4[1].x); lo.h[5] = __float2bfloat16(f4[1].y);
        lo.h[6] = __float2bfloat16(f4[1].z); lo.h[7] = __float2bfloat16(f4[1].w);
        hi.h[0] = __float2bfloat16(f4[2].x); hi.h[1] = __float2bfloat16(f4[2].y);
        hi.h[2] = __float2bfloat16(f4[2].z); hi.h[3] = __float2bfloat16(f4[2].w);
        hi.h[4] = __float2bfloat16(f4[3].x); hi.h[5] = __float2bfloat16(f4[3].y);
        hi.h[6] = __float2bfloat16(f4[3].z); hi.h[7] = __float2bfloat16(f4[3].w);
        As16[r * 8 + gs0] = lo.u;
        As16[r * 8 + gs1] = hi.u;

        __syncthreads();

        // ---- compute: 2 k-steps of 32, 4(M) x 4(N) MFMA tiles per wave ----
#pragma unroll
        for (int ks = 0; ks < 2; ks++) {
            const int gs = (ks * 4 + quad) ^ cl7;
            const v8bf* pa = (const v8bf*)(As + col * BK + gs * 8);
            const v8bf* pb = (const v8bf*)(Bs + (wn + col) * BK + gs * 8);
            v8bf af[4], bfr[4];
#pragma unroll
            for (int mi = 0; mi < 4; mi++) af[mi] = pa[mi * 128];   // +2048 B
#pragma unroll
            for (int ni = 0; ni < 4; ni++) bfr[ni] = pb[ni * 128];
#pragma unroll
            for (int mi = 0; mi < 4; mi++)
#pragma unroll
                for (int ni = 0; ni < 4; ni++)
                    acc[mi][ni] = __builtin_amdgcn_mfma_f32_16x16x32_bf16(
                        af[mi], bfr[ni], acc[mi][ni], 0, 0, 0);
        }
        __syncthreads();
    }

    // ---- epilogue: bias + fast GELU, coalesced fp32 stores ----
#pragma unroll
    for (int ni = 0; ni < 4; ni++) {
        int n    = nt * BN + wn + ni * 16 + col;
        float bv = bias[n];
#pragma unroll
        for (int mi = 0; mi < 4; mi++) {
            int rowb = mt * BM + mi * 16 + quad * 4;
            float* po = out + (size_t)rowb * NN + n;
#pragma unroll
            for (int rg = 0; rg < 4; rg++) {
                float x = acc[mi][ni][rg] + bv;
                po[(size_t)rg * NN] = gelu_fast(x);
            }
        }
    }
}

extern "C" void kernel_launch(void* const* d_in, const int* in_sizes, int n_in,
                              void* d_out, int out_size, void* d_ws, size_t ws_size,
                              hipStream_t stream) {
    const float* img   = (const float*)d_in[0];   // [64,224,224,3]
    const float* wproj = (const float*)d_in[1];   // [768,768]
    const float* bias  = (const float*)d_in[2];   // [768]
    float* out = (float*)d_out;                   // [64,196,768]

    __hip_bfloat16* wpack = (__hip_bfloat16*)d_ws;   // 1,179,648 B used

    wt_pack<<<dim3(WTPACK_BLOCKS), dim3(256), 0, stream>>>(wproj, wpack);
    gemm_gelu<<<dim3(MT * NT), dim3(256), 0, stream>>>(img, wpack, bias, out);
}